// Round 15
// baseline (89.888 us; speedup 1.0000x reference)
//
#include <hip/hip_runtime.h>
#include <math.h>

#define NLAT 360
#define NLON 720
#define LMAX 360
#define MMAX 361
#define KPADC 384   // stage-1 cols per bc: 192 kf x 2 (s)
#define KFP  192    // folded-k padded length (180 data + 12 zero pad)
#define FT_COLS 736
#define FT_ROWS_PAD 384
#define NJ   32
#define XST  744
#define SLOT 12288  // shorts per m-slot: EO (in), OUTT (out, in place)
#define WLS  200    // stage-2 LDS row stride in shorts (2-way banks)

typedef __attribute__((ext_vector_type(4))) float f32x4;
typedef __attribute__((ext_vector_type(8))) short bf16x8;
typedef __attribute__((ext_vector_type(4))) short bf16x4;

__device__ __forceinline__ short f2bf(float f) {
    union { float f; unsigned u; } v; v.f = f;
    unsigned r = (v.u + 0x7FFFu + ((v.u >> 16) & 1u)) >> 16;
    return (short)r;
}

// ------- kernel 0: bf16 cosine-DFT matrix FT[m][n], pads written as 0 ------
__global__ __launch_bounds__(256) void fill_ft_kernel(short* __restrict__ FT) {
    int idx = blockIdx.x * 256 + threadIdx.x;
    const int total = FT_ROWS_PAD * FT_COLS;
    if (idx >= total) return;
    int n = idx % FT_COLS;
    int m = idx / FT_COLS;
    short val = 0;
    if (m < MMAX && n < NLON) {
        int t = (m * n) % NLON;
        float s, c;
        sincospif((float)t / 360.0f, &s, &c);
        val = f2bf((6.283185307179586f / 720.0f) * c);
    }
    FT[idx] = val;
}

// ---------------- stage 1: x-panel DFT + parity fold (validated r12-r14) ---
__global__ __launch_bounds__(512) void stage1_kernel(const float* __restrict__ x,
                                                     const short* __restrict__ FT,
                                                     short* __restrict__ EO,
                                                     int m0, int cm) {
    __shared__ __align__(16) short Xs[64][XST];
    const int tid  = threadIdx.x;
    const int wav  = tid >> 6;
    const int lane = tid & 63;
    const int col0 = blockIdx.x * 64;
    const int m_hi = (m0 + cm < MMAX) ? (m0 + cm) : MMAX;

    for (int p = tid; p < 64 * 92; p += 512) {
        const int row = p / 92;
        const int c   = p - row * 92;
        const int gb  = col0 + row;
        const int bc  = gb / KPADC;
        const int q   = gb - bc * KPADC;
        const int kf  = q >> 1;
        const int s   = q & 1;
        const int klat = s ? (NLAT - 1 - kf) : kf;
        f32x4 va = {0,0,0,0}, vb = {0,0,0,0};
        if (c < 90 && kf < 180) {
            const float* xp = x + ((size_t)bc * NLAT + klat) * NLON + c * 8;
            va = *(const f32x4*)xp;
            vb = *(const f32x4*)(xp + 4);
        }
        bf16x8 wv;
        #pragma unroll
        for (int e = 0; e < 4; ++e) { wv[e] = f2bf(va[e]); wv[e + 4] = f2bf(vb[e]); }
        *(bf16x8*)&Xs[row][c * 8] = wv;
    }
    __syncthreads();

    const int r    = lane & 15;
    const int kg   = (lane >> 4) * 8;
    const int rowg = (lane >> 4) * 4;

    for (int mb = m0; mb < m_hi; mb += 256) {
        const int mwb = mb + wav * 32;
        if (mwb >= m_hi) continue;
        int mA0 = mwb + r;      if (mA0 > FT_ROWS_PAD - 1) mA0 = FT_ROWS_PAD - 1;
        int mA1 = mwb + 16 + r; if (mA1 > FT_ROWS_PAD - 1) mA1 = FT_ROWS_PAD - 1;
        const short* ap0 = FT + (size_t)mA0 * FT_COLS + kg;
        const short* ap1 = FT + (size_t)mA1 * FT_COLS + kg;

        f32x4 acc0[4] = {{0,0,0,0},{0,0,0,0},{0,0,0,0},{0,0,0,0}};
        f32x4 acc1[4] = {{0,0,0,0},{0,0,0,0},{0,0,0,0},{0,0,0,0}};

        bf16x8 A0c = *(const bf16x8*)ap0;
        bf16x8 A1c = *(const bf16x8*)ap1;
        #pragma unroll
        for (int t = 0; t < 23; ++t) {
            bf16x8 A0n, A1n;
            if (t < 22) {
                A0n = *(const bf16x8*)(ap0 + (t + 1) * 32);
                A1n = *(const bf16x8*)(ap1 + (t + 1) * 32);
            }
            #pragma unroll
            for (int f = 0; f < 4; ++f) {
                bf16x8 bfr = *(const bf16x8*)&Xs[f * 16 + r][t * 32 + kg];
                acc0[f] = __builtin_amdgcn_mfma_f32_16x16x32_bf16(A0c, bfr, acc0[f], 0, 0, 0);
                acc1[f] = __builtin_amdgcn_mfma_f32_16x16x32_bf16(A1c, bfr, acc1[f], 0, 0, 0);
            }
            A0c = A0n; A1c = A1n;
        }

        #pragma unroll
        for (int f = 0; f < 4; ++f) {
            const int col = col0 + f * 16 + r;
            const int bc  = col / KPADC;
            const int q   = col - bc * KPADC;
            const int kf  = q >> 1;
            const int e   = q & 1;
            #pragma unroll
            for (int i = 0; i < 4; ++i) {
                const int ma = mwb + rowg + i;
                const int mc = ma + 16;
                float v0 = acc0[f][i];
                float p0 = __shfl_xor(v0, 1);
                float val0 = e ? (p0 - v0) : (v0 + p0);
                float v1 = acc1[f][i];
                float p1 = __shfl_xor(v1, 1);
                float val1 = e ? (p1 - v1) : (v1 + p1);
                if (ma < m_hi)
                    EO[(((size_t)(ma - m0) * 2 + e) * NJ + bc) * KFP + kf] = f2bf(val0);
                if (mc < m_hi)
                    EO[(((size_t)(mc - m0) * 2 + e) * NJ + bc) * KFP + kf] = f2bf(val1);
            }
        }
    }
}

// ---------------- stage 2: one block per m, W streamed, EO read once -------
// 256 thr = 4 waves = (2 l-tiles/iter) x (2 bc-halves). Per iter: stage 2
// W l-tiles (f32->bf16) into LDS dbuf; ONE __syncthreads per iter. B (EO
// slice) loaded to regs once. C written bf16 to OUTT[m][bc][l] IN the m-slot.
__global__ __launch_bounds__(256) void stage2_kernel(const float* __restrict__ W,
                                                     short* __restrict__ EO,
                                                     int m0, int m_hi) {
    __shared__ __align__(16) short Wl[2][2 * 2 * 16 * WLS];   // 51,200 B

    const int m = m0 + blockIdx.x;
    if (m >= m_hi) return;
    const int lt0 = m >> 5;
    const int nt  = 12 - lt0;
    const int np  = (nt + 1) >> 1;

    const int tid  = threadIdx.x;
    const int wav  = tid >> 6;
    const int lane = tid & 63;
    const int v = wav >> 1, u = wav & 1;
    const int r = lane & 15, kg = (lane >> 4) * 8, rowg = (lane >> 4) * 4;
    const int parE = m & 1;
    short* slot = EO + (size_t)(m - m0) * SLOT;
    const int bcg = u * 16 + r;

    // ---- B upfront (all consumed before first OUTT store via reg deps)
    bf16x8 Be[6], Bo[6];
    {
        const short* bb = slot + (size_t)(u * 16 + r) * KFP + kg;
        #pragma unroll
        for (int t = 0; t < 6; ++t) {
            Be[t] = *(const bf16x8*)(bb + t * 32);
            Bo[t] = *(const bf16x8*)(bb + 32 * KFP + t * 32);
        }
    }

    const int aEo = ((v * 2 + parE) * 16 + r) * WLS + kg;
    const int aOo = ((v * 2 + (1 - parE)) * 16 + r) * WLS + kg;

    f32x4 Lv[12];

#define S2_LOADP(p)                                                            \
    _Pragma("unroll")                                                          \
    for (int i = 0; i < 12; ++i) {                                             \
        const int cr  = tid + (i % 6) * 256;                                   \
        const int ts  = i / 6;                                                 \
        const int row = cr / 48;                                               \
        const int q16 = cr - row * 48;                                         \
        int L = (lt0 + 2 * (p) + ts) * 32 + row;                               \
        if (L > LMAX - 1) L = LMAX - 1;                                        \
        Lv[i] = *(const f32x4*)(W + ((size_t)m * LMAX + L) * NLAT + q16 * 4);  \
    }

#define S2_CVW(b)                                                              \
    _Pragma("unroll")                                                          \
    for (int i = 0; i < 12; ++i) {                                             \
        const int cr  = tid + (i % 6) * 256;                                   \
        const int ts  = i / 6;                                                 \
        const int row = cr / 48;                                               \
        const int q16 = cr - row * 48;                                         \
        bf16x4 h;                                                              \
        _Pragma("unroll")                                                      \
        for (int e = 0; e < 4; ++e) h[e] = f2bf(Lv[i][e]);                     \
        *(bf16x4*)&Wl[b][((ts * 2 + (row & 1)) * 16 + (row >> 1)) * WLS + q16 * 4] = h; \
    }

    S2_LOADP(0);
    S2_CVW(0);
    __syncthreads();

    for (int p = 0; p < np; ++p) {
        if (p + 1 < np) { S2_LOADP(p + 1); }
        // compute tile lt0 + 2p + v from buf p&1
        {
            const short* bb = &Wl[p & 1][0];
            f32x4 accE = {0,0,0,0}, accO = {0,0,0,0};
            #pragma unroll
            for (int t = 0; t < 6; ++t) {
                bf16x8 aE = *(const bf16x8*)&bb[aEo + t * 32];
                bf16x8 aO = *(const bf16x8*)&bb[aOo + t * 32];
                accE = __builtin_amdgcn_mfma_f32_16x16x32_bf16(aE, Be[t], accE, 0, 0, 0);
                accO = __builtin_amdgcn_mfma_f32_16x16x32_bf16(aO, Bo[t], accO, 0, 0, 0);
            }
            if (2 * p + v < nt) {
                const int l0s = (lt0 + 2 * p + v) * 32;
                #pragma unroll
                for (int i = 0; i < 4; ++i) {
                    const int le = l0s + parE + 2 * (rowg + i);
                    const int lo = l0s + (1 - parE) + 2 * (rowg + i);
                    if (le < LMAX) slot[bcg * LMAX + le] = f2bf(accE[i]);
                    if (lo < LMAX) slot[bcg * LMAX + lo] = f2bf(accO[i]);
                }
            }
        }
        if (p + 1 < np) { S2_CVW((p + 1) & 1); }
        __syncthreads();
    }
#undef S2_LOADP
#undef S2_CVW
}

// ---------------- stage 3: transpose OUTT[m][bc][l] bf16 -> out[bc][l][m] --
// Grid (12 l-tiles, 32 bc), 256 thr: thread (l = lb + t&31, m-group t>>5).
// Reads 2B strided (L2/L3); writes 46 contiguous floats per thread.
__global__ __launch_bounds__(256) void transpose_kernel(const short* __restrict__ OUTT,
                                                        float* __restrict__ out,
                                                        int m0, int m_hi) {
    const int lb = blockIdx.x * 32;
    const int bc = blockIdx.y;
    const int t  = threadIdx.x;
    const int l  = lb + (t & 31);
    if (l >= LMAX) return;
    const int mlo = (t >> 5) * 46;
    const short* src = OUTT + (size_t)bc * LMAX + l;
    float* dst = out + ((size_t)bc * LMAX + l) * MMAX;
    for (int j = 0; j < 46; ++j) {
        const int m = mlo + j;
        if (m >= MMAX) break;
        if (m < m0 || m >= m_hi) continue;
        union { unsigned u; float f; } cv;
        cv.u = ((unsigned)(unsigned short)src[(size_t)(m - m0) * SLOT]) << 16;
        dst[m] = (l >= ((m >> 5) << 5)) ? cv.f : 0.0f;
    }
}

extern "C" void kernel_launch(void* const* d_in, const int* in_sizes, int n_in,
                              void* d_out, int out_size, void* d_ws, size_t ws_size,
                              hipStream_t stream) {
    const float* x = (const float*)d_in[0];
    const float* w = (const float*)d_in[1];
    float* out = (float*)d_out;

    const size_t XR_OFF = (size_t)FT_ROWS_PAD * FT_COLS * 2;  // 565,248 B
    const size_t PER_M  = (size_t)SLOT * 2;                   // 24,576 B per mode
    long cm = 0;
    if (d_ws != nullptr && ws_size > XR_OFF + PER_M) cm = (long)((ws_size - XR_OFF) / PER_M);
    if (cm > MMAX) cm = MMAX;
    if (cm < 1) return;  // ws proven >= 10.05 MB in round 5; unreachable

    short* FT = (short*)d_ws;
    short* EO = (short*)((char*)d_ws + XR_OFF);
    fill_ft_kernel<<<(FT_ROWS_PAD * FT_COLS + 255) / 256, 256, 0, stream>>>(FT);
    for (int m0 = 0; m0 < MMAX; m0 += (int)cm) {
        const int cmx = ((int)cm < MMAX - m0) ? (int)cm : (MMAX - m0);
        stage1_kernel<<<dim3(192), 512, 0, stream>>>(x, FT, EO, m0, cmx);
        stage2_kernel<<<dim3(cmx), 256, 0, stream>>>(w, EO, m0, m0 + cmx);
        transpose_kernel<<<dim3(12, 32), 256, 0, stream>>>(EO, out, m0, m0 + cmx);
    }
}

// Round 16
// 70.330 us; speedup vs baseline: 1.2781x; 1.2781x over previous
//
#include <hip/hip_runtime.h>
#include <math.h>

#define NLAT 360
#define NLON 720
#define LMAX 360
#define MMAX 361
#define KPADC 384   // stage-1 cols per bc: 192 kf x 2 (s)
#define KFP  192    // folded-k padded length (180 data + 12 zero pad)
#define FT_COLS 736
#define FT_ROWS_PAD 384
#define NJ   32
#define XST  744

typedef __attribute__((ext_vector_type(4))) float f32x4;
typedef __attribute__((ext_vector_type(8))) short bf16x8;
typedef __attribute__((ext_vector_type(4))) short bf16x4;

__device__ __forceinline__ short f2bf(float f) {
    union { float f; unsigned u; } v; v.f = f;
    unsigned r = (v.u + 0x7FFFu + ((v.u >> 16) & 1u)) >> 16;
    return (short)r;
}

// ------- kernel 0: bf16 cosine-DFT matrix FT[m][n], pads written as 0 ------
__global__ __launch_bounds__(256) void fill_ft_kernel(short* __restrict__ FT) {
    int idx = blockIdx.x * 256 + threadIdx.x;
    const int total = FT_ROWS_PAD * FT_COLS;
    if (idx >= total) return;
    int n = idx % FT_COLS;
    int m = idx / FT_COLS;
    short val = 0;
    if (m < MMAX && n < NLON) {
        int t = (m * n) % NLON;
        float s, c;
        sincospif((float)t / 360.0f, &s, &c);
        val = f2bf((6.283185307179586f / 720.0f) * c);
    }
    FT[idx] = val;
}

// ---------------- stage 1: x-panel DFT + parity fold (validated r12-r15) ---
__global__ __launch_bounds__(512) void stage1_kernel(const float* __restrict__ x,
                                                     const short* __restrict__ FT,
                                                     short* __restrict__ EO,
                                                     int m0, int cm) {
    __shared__ __align__(16) short Xs[64][XST];
    const int tid  = threadIdx.x;
    const int wav  = tid >> 6;
    const int lane = tid & 63;
    const int col0 = blockIdx.x * 64;
    const int m_hi = (m0 + cm < MMAX) ? (m0 + cm) : MMAX;

    for (int p = tid; p < 64 * 92; p += 512) {
        const int row = p / 92;
        const int c   = p - row * 92;
        const int gb  = col0 + row;
        const int bc  = gb / KPADC;
        const int q   = gb - bc * KPADC;
        const int kf  = q >> 1;
        const int s   = q & 1;
        const int klat = s ? (NLAT - 1 - kf) : kf;
        f32x4 va = {0,0,0,0}, vb = {0,0,0,0};
        if (c < 90 && kf < 180) {
            const float* xp = x + ((size_t)bc * NLAT + klat) * NLON + c * 8;
            va = *(const f32x4*)xp;
            vb = *(const f32x4*)(xp + 4);
        }
        bf16x8 wv;
        #pragma unroll
        for (int e = 0; e < 4; ++e) { wv[e] = f2bf(va[e]); wv[e + 4] = f2bf(vb[e]); }
        *(bf16x8*)&Xs[row][c * 8] = wv;
    }
    __syncthreads();

    const int r    = lane & 15;
    const int kg   = (lane >> 4) * 8;
    const int rowg = (lane >> 4) * 4;

    for (int mb = m0; mb < m_hi; mb += 256) {
        const int mwb = mb + wav * 32;
        if (mwb >= m_hi) continue;
        int mA0 = mwb + r;      if (mA0 > FT_ROWS_PAD - 1) mA0 = FT_ROWS_PAD - 1;
        int mA1 = mwb + 16 + r; if (mA1 > FT_ROWS_PAD - 1) mA1 = FT_ROWS_PAD - 1;
        const short* ap0 = FT + (size_t)mA0 * FT_COLS + kg;
        const short* ap1 = FT + (size_t)mA1 * FT_COLS + kg;

        f32x4 acc0[4] = {{0,0,0,0},{0,0,0,0},{0,0,0,0},{0,0,0,0}};
        f32x4 acc1[4] = {{0,0,0,0},{0,0,0,0},{0,0,0,0},{0,0,0,0}};

        bf16x8 A0c = *(const bf16x8*)ap0;
        bf16x8 A1c = *(const bf16x8*)ap1;
        #pragma unroll
        for (int t = 0; t < 23; ++t) {
            bf16x8 A0n, A1n;
            if (t < 22) {
                A0n = *(const bf16x8*)(ap0 + (t + 1) * 32);
                A1n = *(const bf16x8*)(ap1 + (t + 1) * 32);
            }
            #pragma unroll
            for (int f = 0; f < 4; ++f) {
                bf16x8 bfr = *(const bf16x8*)&Xs[f * 16 + r][t * 32 + kg];
                acc0[f] = __builtin_amdgcn_mfma_f32_16x16x32_bf16(A0c, bfr, acc0[f], 0, 0, 0);
                acc1[f] = __builtin_amdgcn_mfma_f32_16x16x32_bf16(A1c, bfr, acc1[f], 0, 0, 0);
            }
            A0c = A0n; A1c = A1n;
        }

        #pragma unroll
        for (int f = 0; f < 4; ++f) {
            const int col = col0 + f * 16 + r;
            const int bc  = col / KPADC;
            const int q   = col - bc * KPADC;
            const int kf  = q >> 1;
            const int e   = q & 1;
            #pragma unroll
            for (int i = 0; i < 4; ++i) {
                const int ma = mwb + rowg + i;
                const int mc = ma + 16;
                float v0 = acc0[f][i];
                float p0 = __shfl_xor(v0, 1);
                float val0 = e ? (p0 - v0) : (v0 + p0);
                float v1 = acc1[f][i];
                float p1 = __shfl_xor(v1, 1);
                float val1 = e ? (p1 - v1) : (v1 + p1);
                if (ma < m_hi)
                    EO[(((size_t)(ma - m0) * 2 + e) * NJ + bc) * KFP + kf] = f2bf(val0);
                if (mc < m_hi)
                    EO[(((size_t)(mc - m0) * 2 + e) * NJ + bc) * KFP + kf] = f2bf(val1);
            }
        }
    }
}

// ---------------- stage 2: r13 geometry + counted-vmcnt raw barriers -------
// Block 256 thr = 4 waves = 4 m; tile 32l x 32bc x 4m, K = 6 steps of 32.
// 3-deep register pipeline (sets A/B/C); ONE raw barrier per K-step with
// lgkmcnt(0) only -- global prefetch loads stay in flight across barriers.
#define S2_GW(P, T)                                                             \
  { P##wa = *(const f32x4*)(wsp0 + (T) * 32);                                   \
    P##wb = *(const f32x4*)(wsp0 + (T) * 32 + 4);                               \
    P##wc = *(const f32x4*)(wsp1 + (T) * 32);                                   \
    P##wd = *(const f32x4*)(wsp1 + (T) * 32 + 4); }

#define S2_GB(P, T)                                                             \
  { P##ba = *(const bf16x8*)(be0 + (T) * 32);                                   \
    P##bb = *(const bf16x8*)(be1 + (T) * 32);                                   \
    P##bc = *(const bf16x8*)(bo0 + (T) * 32);                                   \
    P##bd = *(const bf16x8*)(bo1 + (T) * 32); }

#define S2_WRT(P, BUF)                                                          \
  { bf16x8 h0, h1;                                                              \
    _Pragma("unroll")                                                           \
    for (int e = 0; e < 4; ++e) {                                               \
      h0[e] = f2bf(P##wa[e]); h0[e + 4] = f2bf(P##wb[e]);                       \
      h1[e] = f2bf(P##wc[e]); h1[e + 4] = f2bf(P##wd[e]);                       \
    }                                                                           \
    *(bf16x8*)&Wl[BUF][ldso0] = h0;                                             \
    *(bf16x8*)&Wl[BUF][ldso1] = h1; }

#define S2_SYNC                                                                 \
    asm volatile("s_waitcnt lgkmcnt(0)" ::: "memory");                          \
    __builtin_amdgcn_s_barrier();                                               \
    __builtin_amdgcn_sched_barrier(0);

#define S2_CMP(P, BUF)                                                          \
  { bf16x8 aEf = *(const bf16x8*)&Wl[BUF][aEo];                                 \
    bf16x8 aOf = *(const bf16x8*)&Wl[BUF][aOo];                                 \
    accE0 = __builtin_amdgcn_mfma_f32_16x16x32_bf16(aEf, P##ba, accE0, 0, 0, 0);\
    accE1 = __builtin_amdgcn_mfma_f32_16x16x32_bf16(aEf, P##bb, accE1, 0, 0, 0);\
    accO0 = __builtin_amdgcn_mfma_f32_16x16x32_bf16(aOf, P##bc, accO0, 0, 0, 0);\
    accO1 = __builtin_amdgcn_mfma_f32_16x16x32_bf16(aOf, P##bd, accO1, 0, 0, 0);}

__global__ __launch_bounds__(256) void stage2_kernel(const float* __restrict__ W,
                                                     const short* __restrict__ EO,
                                                     float* __restrict__ out,
                                                     int m0, int m_hi) {
    __shared__ __align__(16) short Wl[2][4 * 2 * 17 * 40];   // 2 x 10,880 B

    // compacted grid decode: blocks per 4-m tile = 12 - ((m0 + mt*4) >> 5)
    int bid = blockIdx.x;
    int mt = 0;
    for (;;) {
        const int c = 12 - ((m0 + mt * 4) >> 5);
        if (bid < c) break;
        bid -= c; ++mt;
    }
    const int ltile = ((m0 + mt * 4) >> 5) + bid;
    const int l0 = ltile * 32;                  // even
    const int mb = m0 + mt * 4;

    const int tid  = threadIdx.x;
    const int wav  = tid >> 6;                  // 0..3 = m offset
    const int lane = tid & 63;
    const int r    = lane & 15;
    const int kg   = (lane >> 4) * 8;

    const int m    = mb + wav;
    const int mc   = (m < m_hi) ? m : (m_hi - 1);
    const int par  = mc & 1;
    const int mloc = mc - m0;

    // staging: 128 rows (4m x 32l) x 32k per step; 4 threads/row, 8 floats each
    const int srr = tid >> 2;                   // 0..63
    const int sq  = (tid & 3) * 8;              // k offset (floats)
    const int moff0 = srr >> 5,        loff0 = srr & 31;
    const int moff1 = (64 + srr) >> 5, loff1 = (64 + srr) & 31;
    int mst0 = mb + moff0; if (mst0 > MMAX - 1) mst0 = MMAX - 1;
    int mst1 = mb + moff1; if (mst1 > MMAX - 1) mst1 = MMAX - 1;
    int lst0 = l0 + loff0; if (lst0 > LMAX - 1) lst0 = LMAX - 1;
    int lst1 = l0 + loff1; if (lst1 > LMAX - 1) lst1 = LMAX - 1;
    const float* wsp0 = W + ((size_t)mst0 * LMAX + lst0) * NLAT + sq;
    const float* wsp1 = W + ((size_t)mst1 * LMAX + lst1) * NLAT + sq;
    const int ldso0 = ((moff0 * 2 + (loff0 & 1)) * 17 + (loff0 >> 1)) * 40 + sq;
    const int ldso1 = ((moff1 * 2 + (loff1 & 1)) * 17 + (loff1 >> 1)) * 40 + sq;

    // B pointers (EO, per-lane; L2/L3-resident)
    const short* be0 = EO + (((size_t)mloc * 2 + 0) * NJ + r)      * KFP + kg;
    const short* be1 = EO + (((size_t)mloc * 2 + 0) * NJ + 16 + r) * KFP + kg;
    const short* bo0 = EO + (((size_t)mloc * 2 + 1) * NJ + r)      * KFP + kg;
    const short* bo1 = EO + (((size_t)mloc * 2 + 1) * NJ + 16 + r) * KFP + kg;

    // A fragment LDS offsets
    const int aEo = ((wav * 2 + par) * 17 + r) * 40 + kg;
    const int aOo = ((wav * 2 + (1 - par)) * 17 + r) * 40 + kg;

    f32x4 accE0 = {0,0,0,0}, accE1 = {0,0,0,0}, accO0 = {0,0,0,0}, accO1 = {0,0,0,0};

    f32x4 Awa, Awb, Awc, Awd, Bwa, Bwb, Bwc, Bwd, Cwa, Cwb, Cwc, Cwd;
    bf16x8 Aba, Abb, Abc, Abd, Bba, Bbb, Bbc, Bbd, Cba, Cbb, Cbc, Cbd;

    // prologue: 3 K-steps in flight
    S2_GW(A, 0); S2_GB(A, 0);
    S2_GW(B, 1); S2_GB(B, 1);
    S2_GW(C, 2); S2_GB(C, 2);

    // t=0
    S2_WRT(A, 0); S2_SYNC; S2_CMP(A, 0); S2_GW(A, 3); S2_GB(A, 3);
    // t=1
    S2_WRT(B, 1); S2_SYNC; S2_CMP(B, 1); S2_GW(B, 4); S2_GB(B, 4);
    // t=2
    S2_WRT(C, 0); S2_SYNC; S2_CMP(C, 0); S2_GW(C, 5); S2_GB(C, 5);
    // t=3
    S2_WRT(A, 1); S2_SYNC; S2_CMP(A, 1);
    // t=4
    S2_WRT(B, 0); S2_SYNC; S2_CMP(B, 0);
    // t=5
    S2_WRT(C, 1); S2_SYNC; S2_CMP(C, 1);

    // epilogue (identical to r13): row R -> l = l0+par+2R (E) / l0+1-par+2R (O)
    const int rowg = (lane >> 4) * 4;
    if (m < m_hi) {
        #pragma unroll
        for (int i = 0; i < 4; ++i) {
            const int R  = rowg + i;
            const int le = l0 + par + 2 * R;
            const int lo = l0 + 1 - par + 2 * R;
            const size_t b0 = (size_t)r * LMAX;
            const size_t b1 = (size_t)(16 + r) * LMAX;
            if (le < LMAX) {
                out[(b0 + le) * MMAX + m] = accE0[i];
                out[(b1 + le) * MMAX + m] = accE1[i];
            }
            if (lo < LMAX) {
                out[(b0 + lo) * MMAX + m] = accO0[i];
                out[(b1 + lo) * MMAX + m] = accO1[i];
            }
        }
    }
}

extern "C" void kernel_launch(void* const* d_in, const int* in_sizes, int n_in,
                              void* d_out, int out_size, void* d_ws, size_t ws_size,
                              hipStream_t stream) {
    const float* x = (const float*)d_in[0];
    const float* w = (const float*)d_in[1];
    float* out = (float*)d_out;

    const size_t XR_OFF = (size_t)FT_ROWS_PAD * FT_COLS * 2;  // 565,248 B
    const size_t PER_M  = (size_t)2 * NJ * KFP * 2;           // 24,576 B per mode
    long cm = 0;
    if (d_ws != nullptr && ws_size > XR_OFF + PER_M) cm = (long)((ws_size - XR_OFF) / PER_M);
    if (cm > MMAX) cm = MMAX;
    if (cm < 1) return;

    short* FT = (short*)d_ws;
    short* EO = (short*)((char*)d_ws + XR_OFF);
    fill_ft_kernel<<<(FT_ROWS_PAD * FT_COLS + 255) / 256, 256, 0, stream>>>(FT);
    for (int m0 = 0; m0 < MMAX; m0 += (int)cm) {
        const int cmx = ((int)cm < MMAX - m0) ? (int)cm : (MMAX - m0);
        stage1_kernel<<<dim3(192), 512, 0, stream>>>(x, FT, EO, m0, cmx);
        const int gym = (cmx + 3) / 4;
        int nblk = 0;
        for (int mtt = 0; mtt < gym; ++mtt) nblk += 12 - ((m0 + mtt * 4) >> 5);
        stage2_kernel<<<dim3(nblk), 256, 0, stream>>>(w, EO, out, m0, m0 + cmx);
    }
}

// Round 17
// 69.568 us; speedup vs baseline: 1.2921x; 1.0109x over previous
//
#include <hip/hip_runtime.h>
#include <math.h>

#define NLAT 360
#define NLON 720
#define LMAX 360
#define MMAX 361
#define KPADC 384   // stage-1 cols per bc: 192 kf x 2 (s)
#define KFP  192    // folded-k padded length (180 data + 12 zero pad)
#define FT_COLS 736
#define FT_ROWS_PAD 384
#define NJ   32
#define XST  744
#define YST  72     // Ys row stride (shorts): 144B, 16B-aligned, ~4-way banks

typedef __attribute__((ext_vector_type(4))) float f32x4;
typedef __attribute__((ext_vector_type(8))) short bf16x8;

__device__ __forceinline__ short f2bf(float f) {
    union { float f; unsigned u; } v; v.f = f;
    unsigned r = (v.u + 0x7FFFu + ((v.u >> 16) & 1u)) >> 16;
    return (short)r;
}

// ------- kernel 0: bf16 cosine-DFT matrix FT[m][n], pads written as 0 ------
__global__ __launch_bounds__(256) void fill_ft_kernel(short* __restrict__ FT) {
    int idx = blockIdx.x * 256 + threadIdx.x;
    const int total = FT_ROWS_PAD * FT_COLS;
    if (idx >= total) return;
    int n = idx % FT_COLS;
    int m = idx / FT_COLS;
    short val = 0;
    if (m < MMAX && n < NLON) {
        int t = (m * n) % NLON;
        float s, c;
        sincospif((float)t / 360.0f, &s, &c);
        val = f2bf((6.283185307179586f / 720.0f) * c);
    }
    FT[idx] = val;
}

// ---------------- stage 1: x-panel DFT + parity fold ----------------------
// NEW epilogue: fold -> Ys (LDS transpose) -> full-line coalesced EO stores.
__global__ __launch_bounds__(512) void stage1_kernel(const float* __restrict__ x,
                                                     const short* __restrict__ FT,
                                                     short* __restrict__ EO,
                                                     int m0, int cm) {
    __shared__ __align__(16) short Xs[64][XST];     // 95,232 B
    __shared__ __align__(16) short Ys[256 * YST];   // 36,864 B
    const int tid  = threadIdx.x;
    const int wav  = tid >> 6;
    const int lane = tid & 63;
    const int col0 = blockIdx.x * 64;
    const int m_hi = (m0 + cm < MMAX) ? (m0 + cm) : MMAX;

    const int bc_blk = col0 / KPADC;          // 384 % 64 == 0: one bc per block
    const int kf0    = (col0 - bc_blk * KPADC) >> 1;

    for (int p = tid; p < 64 * 92; p += 512) {
        const int row = p / 92;
        const int c   = p - row * 92;
        const int gb  = col0 + row;
        const int bc  = gb / KPADC;
        const int q   = gb - bc * KPADC;
        const int kf  = q >> 1;
        const int s   = q & 1;
        const int klat = s ? (NLAT - 1 - kf) : kf;
        f32x4 va = {0,0,0,0}, vb = {0,0,0,0};
        if (c < 90 && kf < 180) {
            const float* xp = x + ((size_t)bc * NLAT + klat) * NLON + c * 8;
            va = *(const f32x4*)xp;
            vb = *(const f32x4*)(xp + 4);
        }
        bf16x8 wv;
        #pragma unroll
        for (int e = 0; e < 4; ++e) { wv[e] = f2bf(va[e]); wv[e + 4] = f2bf(vb[e]); }
        *(bf16x8*)&Xs[row][c * 8] = wv;
    }
    __syncthreads();

    const int r    = lane & 15;
    const int kg   = (lane >> 4) * 8;
    const int rowg = (lane >> 4) * 4;

    for (int mb = m0; mb < m_hi; mb += 256) {
        const int mwb = mb + wav * 32;
        const bool active = (mwb < m_hi);      // wave-uniform

        if (active) {
            int mA0 = mwb + r;      if (mA0 > FT_ROWS_PAD - 1) mA0 = FT_ROWS_PAD - 1;
            int mA1 = mwb + 16 + r; if (mA1 > FT_ROWS_PAD - 1) mA1 = FT_ROWS_PAD - 1;
            const short* ap0 = FT + (size_t)mA0 * FT_COLS + kg;
            const short* ap1 = FT + (size_t)mA1 * FT_COLS + kg;

            f32x4 acc0[4] = {{0,0,0,0},{0,0,0,0},{0,0,0,0},{0,0,0,0}};
            f32x4 acc1[4] = {{0,0,0,0},{0,0,0,0},{0,0,0,0},{0,0,0,0}};

            bf16x8 A0c = *(const bf16x8*)ap0;
            bf16x8 A1c = *(const bf16x8*)ap1;
            #pragma unroll
            for (int t = 0; t < 23; ++t) {
                bf16x8 A0n, A1n;
                if (t < 22) {
                    A0n = *(const bf16x8*)(ap0 + (t + 1) * 32);
                    A1n = *(const bf16x8*)(ap1 + (t + 1) * 32);
                }
                #pragma unroll
                for (int f = 0; f < 4; ++f) {
                    bf16x8 bfr = *(const bf16x8*)&Xs[f * 16 + r][t * 32 + kg];
                    acc0[f] = __builtin_amdgcn_mfma_f32_16x16x32_bf16(A0c, bfr, acc0[f], 0, 0, 0);
                    acc1[f] = __builtin_amdgcn_mfma_f32_16x16x32_bf16(A1c, bfr, acc1[f], 0, 0, 0);
                }
                A0c = A0n; A1c = A1n;
            }

            // fold pairs across adjacent lanes, write transposed into Ys
            #pragma unroll
            for (int f = 0; f < 4; ++f) {
                const int kfl = (f * 16 + r) >> 1;
                const int e   = r & 1;
                const int yo  = e * 32 + kfl;
                #pragma unroll
                for (int i = 0; i < 4; ++i) {
                    float v0 = acc0[f][i];
                    float p0 = __shfl_xor(v0, 1);
                    float val0 = e ? (p0 - v0) : (v0 + p0);
                    float v1 = acc1[f][i];
                    float p1 = __shfl_xor(v1, 1);
                    float val1 = e ? (p1 - v1) : (v1 + p1);
                    Ys[(wav * 32 + rowg + i) * YST + yo]      = f2bf(val0);
                    Ys[(wav * 32 + 16 + rowg + i) * YST + yo] = f2bf(val1);
                }
            }
        }
        __syncthreads();

        // coalesced EO store: thread -> (m_loc, e); one full 64B line each
        {
            const int m_loc = tid >> 1;
            const int e     = tid & 1;
            const int mg    = mb + m_loc;
            if (mg < m_hi) {
                const short* src = &Ys[m_loc * YST + e * 32];
                short* dst = EO + (((size_t)(mg - m0) * 2 + e) * NJ + bc_blk) * KFP + kf0;
                #pragma unroll
                for (int j = 0; j < 4; ++j)
                    *(bf16x8*)(dst + j * 8) = *(const bf16x8*)(src + j * 8);
            }
        }
        __syncthreads();
    }
}

// ---------------- stage 2: r16 verbatim (counted-vmcnt raw barriers) -------
#define S2_GW(P, T)                                                             \
  { P##wa = *(const f32x4*)(wsp0 + (T) * 32);                                   \
    P##wb = *(const f32x4*)(wsp0 + (T) * 32 + 4);                               \
    P##wc = *(const f32x4*)(wsp1 + (T) * 32);                                   \
    P##wd = *(const f32x4*)(wsp1 + (T) * 32 + 4); }

#define S2_GB(P, T)                                                             \
  { P##ba = *(const bf16x8*)(be0 + (T) * 32);                                   \
    P##bb = *(const bf16x8*)(be1 + (T) * 32);                                   \
    P##bc = *(const bf16x8*)(bo0 + (T) * 32);                                   \
    P##bd = *(const bf16x8*)(bo1 + (T) * 32); }

#define S2_WRT(P, BUF)                                                          \
  { bf16x8 h0, h1;                                                              \
    _Pragma("unroll")                                                           \
    for (int e = 0; e < 4; ++e) {                                               \
      h0[e] = f2bf(P##wa[e]); h0[e + 4] = f2bf(P##wb[e]);                       \
      h1[e] = f2bf(P##wc[e]); h1[e + 4] = f2bf(P##wd[e]);                       \
    }                                                                           \
    *(bf16x8*)&Wl[BUF][ldso0] = h0;                                             \
    *(bf16x8*)&Wl[BUF][ldso1] = h1; }

#define S2_SYNC                                                                 \
    asm volatile("s_waitcnt lgkmcnt(0)" ::: "memory");                          \
    __builtin_amdgcn_s_barrier();                                               \
    __builtin_amdgcn_sched_barrier(0);

#define S2_CMP(P, BUF)                                                          \
  { bf16x8 aEf = *(const bf16x8*)&Wl[BUF][aEo];                                 \
    bf16x8 aOf = *(const bf16x8*)&Wl[BUF][aOo];                                 \
    accE0 = __builtin_amdgcn_mfma_f32_16x16x32_bf16(aEf, P##ba, accE0, 0, 0, 0);\
    accE1 = __builtin_amdgcn_mfma_f32_16x16x32_bf16(aEf, P##bb, accE1, 0, 0, 0);\
    accO0 = __builtin_amdgcn_mfma_f32_16x16x32_bf16(aOf, P##bc, accO0, 0, 0, 0);\
    accO1 = __builtin_amdgcn_mfma_f32_16x16x32_bf16(aOf, P##bd, accO1, 0, 0, 0);}

__global__ __launch_bounds__(256) void stage2_kernel(const float* __restrict__ W,
                                                     const short* __restrict__ EO,
                                                     float* __restrict__ out,
                                                     int m0, int m_hi) {
    __shared__ __align__(16) short Wl[2][4 * 2 * 17 * 40];   // 2 x 10,880 B

    int bid = blockIdx.x;
    int mt = 0;
    for (;;) {
        const int c = 12 - ((m0 + mt * 4) >> 5);
        if (bid < c) break;
        bid -= c; ++mt;
    }
    const int ltile = ((m0 + mt * 4) >> 5) + bid;
    const int l0 = ltile * 32;                  // even
    const int mb = m0 + mt * 4;

    const int tid  = threadIdx.x;
    const int wav  = tid >> 6;                  // 0..3 = m offset
    const int lane = tid & 63;
    const int r    = lane & 15;
    const int kg   = (lane >> 4) * 8;

    const int m    = mb + wav;
    const int mc   = (m < m_hi) ? m : (m_hi - 1);
    const int par  = mc & 1;
    const int mloc = mc - m0;

    const int srr = tid >> 2;
    const int sq  = (tid & 3) * 8;
    const int moff0 = srr >> 5,        loff0 = srr & 31;
    const int moff1 = (64 + srr) >> 5, loff1 = (64 + srr) & 31;
    int mst0 = mb + moff0; if (mst0 > MMAX - 1) mst0 = MMAX - 1;
    int mst1 = mb + moff1; if (mst1 > MMAX - 1) mst1 = MMAX - 1;
    int lst0 = l0 + loff0; if (lst0 > LMAX - 1) lst0 = LMAX - 1;
    int lst1 = l0 + loff1; if (lst1 > LMAX - 1) lst1 = LMAX - 1;
    const float* wsp0 = W + ((size_t)mst0 * LMAX + lst0) * NLAT + sq;
    const float* wsp1 = W + ((size_t)mst1 * LMAX + lst1) * NLAT + sq;
    const int ldso0 = ((moff0 * 2 + (loff0 & 1)) * 17 + (loff0 >> 1)) * 40 + sq;
    const int ldso1 = ((moff1 * 2 + (loff1 & 1)) * 17 + (loff1 >> 1)) * 40 + sq;

    const short* be0 = EO + (((size_t)mloc * 2 + 0) * NJ + r)      * KFP + kg;
    const short* be1 = EO + (((size_t)mloc * 2 + 0) * NJ + 16 + r) * KFP + kg;
    const short* bo0 = EO + (((size_t)mloc * 2 + 1) * NJ + r)      * KFP + kg;
    const short* bo1 = EO + (((size_t)mloc * 2 + 1) * NJ + 16 + r) * KFP + kg;

    const int aEo = ((wav * 2 + par) * 17 + r) * 40 + kg;
    const int aOo = ((wav * 2 + (1 - par)) * 17 + r) * 40 + kg;

    f32x4 accE0 = {0,0,0,0}, accE1 = {0,0,0,0}, accO0 = {0,0,0,0}, accO1 = {0,0,0,0};

    f32x4 Awa, Awb, Awc, Awd, Bwa, Bwb, Bwc, Bwd, Cwa, Cwb, Cwc, Cwd;
    bf16x8 Aba, Abb, Abc, Abd, Bba, Bbb, Bbc, Bbd, Cba, Cbb, Cbc, Cbd;

    S2_GW(A, 0); S2_GB(A, 0);
    S2_GW(B, 1); S2_GB(B, 1);
    S2_GW(C, 2); S2_GB(C, 2);

    S2_WRT(A, 0); S2_SYNC; S2_CMP(A, 0); S2_GW(A, 3); S2_GB(A, 3);
    S2_WRT(B, 1); S2_SYNC; S2_CMP(B, 1); S2_GW(B, 4); S2_GB(B, 4);
    S2_WRT(C, 0); S2_SYNC; S2_CMP(C, 0); S2_GW(C, 5); S2_GB(C, 5);
    S2_WRT(A, 1); S2_SYNC; S2_CMP(A, 1);
    S2_WRT(B, 0); S2_SYNC; S2_CMP(B, 0);
    S2_WRT(C, 1); S2_SYNC; S2_CMP(C, 1);

    const int rowg = (lane >> 4) * 4;
    if (m < m_hi) {
        #pragma unroll
        for (int i = 0; i < 4; ++i) {
            const int R  = rowg + i;
            const int le = l0 + par + 2 * R;
            const int lo = l0 + 1 - par + 2 * R;
            const size_t b0 = (size_t)r * LMAX;
            const size_t b1 = (size_t)(16 + r) * LMAX;
            if (le < LMAX) {
                out[(b0 + le) * MMAX + m] = accE0[i];
                out[(b1 + le) * MMAX + m] = accE1[i];
            }
            if (lo < LMAX) {
                out[(b0 + lo) * MMAX + m] = accO0[i];
                out[(b1 + lo) * MMAX + m] = accO1[i];
            }
        }
    }
}

extern "C" void kernel_launch(void* const* d_in, const int* in_sizes, int n_in,
                              void* d_out, int out_size, void* d_ws, size_t ws_size,
                              hipStream_t stream) {
    const float* x = (const float*)d_in[0];
    const float* w = (const float*)d_in[1];
    float* out = (float*)d_out;

    const size_t XR_OFF = (size_t)FT_ROWS_PAD * FT_COLS * 2;  // 565,248 B
    const size_t PER_M  = (size_t)2 * NJ * KFP * 2;           // 24,576 B per mode
    long cm = 0;
    if (d_ws != nullptr && ws_size > XR_OFF + PER_M) cm = (long)((ws_size - XR_OFF) / PER_M);
    if (cm > MMAX) cm = MMAX;
    if (cm < 1) return;

    short* FT = (short*)d_ws;
    short* EO = (short*)((char*)d_ws + XR_OFF);
    fill_ft_kernel<<<(FT_ROWS_PAD * FT_COLS + 255) / 256, 256, 0, stream>>>(FT);
    for (int m0 = 0; m0 < MMAX; m0 += (int)cm) {
        const int cmx = ((int)cm < MMAX - m0) ? (int)cm : (MMAX - m0);
        stage1_kernel<<<dim3(192), 512, 0, stream>>>(x, FT, EO, m0, cmx);
        const int gym = (cmx + 3) / 4;
        int nblk = 0;
        for (int mtt = 0; mtt < gym; ++mtt) nblk += 12 - ((m0 + mtt * 4) >> 5);
        stage2_kernel<<<dim3(nblk), 256, 0, stream>>>(w, EO, out, m0, m0 + cmx);
    }
}